// Round 2
// baseline (866.295 us; speedup 1.0000x reference)
//
#include <hip/hip_runtime.h>
#include <hip/hip_bf16.h>

#define S_LEN 2048
#define DM 1024

typedef __attribute__((ext_vector_type(8))) short s16x8;
typedef __attribute__((ext_vector_type(4))) float f32x4;
typedef __attribute__((ext_vector_type(4))) ushort u16x4;

__device__ __forceinline__ ushort f2bf(float f){
  union { float f; unsigned u; } v; v.f = f;
  unsigned r = (v.u + 0x7FFFu + ((v.u >> 16) & 1u)) >> 16;
  return (ushort)r;
}

__device__ __forceinline__ f32x4 mfma16(s16x8 a, s16x8 b, f32x4 c){
  return __builtin_amdgcn_mfma_f32_16x16x32_bf16(a, b, c, 0, 0, 0);
}

__device__ __forceinline__ void gl_lds16(const ushort* g, ushort* l){
  __builtin_amdgcn_global_load_lds(
      (const __attribute__((address_space(1))) unsigned int*)g,
      (__attribute__((address_space(3))) unsigned int*)l, 16, 0, 0);
}

// ---------------- RoPE cos/sin table: tab[t*64 + 2*i2] = cos, +1 = sin ----------------
__global__ __launch_bounds__(256) void trig_kernel(float* __restrict__ tab){
  int idx = blockIdx.x*256 + threadIdx.x;    // 2048*32 entries
  int t = idx >> 5, i2 = idx & 31;
  float inv = exp2f(-(float)i2 * 0.4152410118609203f);  // log2(10000)/32
  float ang = (float)t * inv;
  tab[2*idx]   = cosf(ang);
  tab[2*idx+1] = sinf(ang);
}

// ---------------- LayerNorm: fp32 row -> bf16 row ----------------
__global__ __launch_bounds__(256) void ln_kernel(const float* __restrict__ x,
    const float* __restrict__ g, const float* __restrict__ be, ushort* __restrict__ o){
  int row = blockIdx.x;
  int tid = threadIdx.x;
  const float* xr = x + (size_t)row*DM;
  float4 xv = *(const float4*)(xr + tid*4);
  float s  = xv.x+xv.y+xv.z+xv.w;
  float s2 = xv.x*xv.x+xv.y*xv.y+xv.z*xv.z+xv.w*xv.w;
  for (int m=1;m<64;m<<=1){ s += __shfl_xor(s,m); s2 += __shfl_xor(s2,m); }
  __shared__ float red[8];
  int w = tid>>6, l = tid&63;
  if (l==0){ red[w]=s; red[4+w]=s2; }
  __syncthreads();
  float ts = red[0]+red[1]+red[2]+red[3];
  float t2 = red[4]+red[5]+red[6]+red[7];
  float mu  = ts*(1.0f/DM);
  float var = t2*(1.0f/DM) - mu*mu;
  float rs  = rsqrtf(var + 1e-5f);
  float vals[4] = {xv.x,xv.y,xv.z,xv.w};
  const float* gp = g + tid*4;
  const float* bp = be + tid*4;
  u16x4 ov;
  #pragma unroll
  for (int j=0;j<4;j++) ov[j] = f2bf((vals[j]-mu)*rs*gp[j] + bp[j]);
  *(u16x4*)(o + (size_t)row*DM + tid*4) = ov;
}

// ---------------- Weight transpose + bf16: in[K=1024][N] -> out[N][1024], LDS-tiled ----------------
__global__ __launch_bounds__(256) void wtr_kernel(const float* __restrict__ in,
    ushort* __restrict__ out, int N){
  __shared__ float lsf[32][36];
  int tid = threadIdx.x;
  int n0 = blockIdx.x*32, k0 = blockIdx.y*32;
  int kr = tid>>3, nc = (tid&7)*4;
  float4 v = *(const float4*)(in + (size_t)(k0+kr)*N + n0 + nc);
  *(float4*)&lsf[kr][nc] = v;
  __syncthreads();
  int nr = tid>>3, kc = (tid&7)*4;
  u16x4 o;
  #pragma unroll
  for (int j=0;j<4;j++) o[j] = f2bf(lsf[kc+j][nr]);
  *(u16x4*)(out + (size_t)(n0+nr)*DM + k0 + kc) = o;
}

// ---------------- ushort transpose: vb[n][T][h][d=64] -> vt[(n*4+h)*64 + d][T] ----------------
__global__ __launch_bounds__(256) void utr_kernel(const ushort* __restrict__ vb,
    ushort* __restrict__ vt){
  __shared__ ushort lst[64*72];
  int tid = threadIdx.x;
  int t0 = blockIdx.x*64;
  int y = blockIdx.y; int n = y>>2, h = y&3;
  int Tr = tid>>2, dg = (tid&3)*16;
  const ushort* ip = vb + ((size_t)(n*S_LEN + t0 + Tr))*256 + h*64 + dg;
  *(s16x8*)&lst[Tr*72 + dg]     = *(const s16x8*)ip;
  *(s16x8*)&lst[Tr*72 + dg + 8] = *(const s16x8*)(ip+8);
  __syncthreads();
  int d = tid>>2, Tg = (tid&3)*16;
  ushort* op = vt + ((size_t)(y*64 + d))*S_LEN + t0 + Tg;
  #pragma unroll
  for (int q=0;q<4;q++){
    u16x4 o;
    #pragma unroll
    for (int j=0;j<4;j++) o[j] = lst[(Tg+4*q+j)*72 + d];
    *(u16x4*)(op + 4*q) = o;
  }
}

// ---------------- GEMM: C[M x N] = A[M x K] * BT[N x K]^T + bias, m97-style ----------------
template<int BN, bool ROPE, bool F32OUT>
__global__ __launch_bounds__(256) void gemm_kernel(
    const ushort* __restrict__ A, const ushort* __restrict__ BT,
    const float* __restrict__ bias, const float* __restrict__ tab,
    void* __restrict__ Cv, int N, int K){
  constexpr int NB = BN/32;
  __shared__ ushort Als[128*32];
  __shared__ ushort Bls[BN*32];
  int tid = threadIdx.x;
  int w = tid>>6, l = tid&63, lg = l>>4, li = l&15;
  int wr = w>>1, wc = w&1;
  int mbase = blockIdx.y*128, nbase = blockIdx.x*BN;
  f32x4 acc[4][NB];
  #pragma unroll
  for (int m=0;m<4;m++)
    #pragma unroll
    for (int n=0;n<NB;n++) acc[m][n] = (f32x4){0.f,0.f,0.f,0.f};
  int cr = l>>2, ck = (l&3)*8;
  for (int kk=0; kk<K; kk+=32){
    __syncthreads();
    #pragma unroll
    for (int s=0;s<2;s++){
      int ch = w*2+s;
      gl_lds16(A + (size_t)(mbase + ch*16 + cr)*K + kk + ck, &Als[ch*512]);
    }
    #pragma unroll
    for (int s=0;s<BN/64;s++){
      int ch = w*(BN/64)+s;
      gl_lds16(BT + (size_t)(nbase + ch*16 + cr)*K + kk + ck, &Bls[ch*512]);
    }
    __syncthreads();
    s16x8 af[4], bf[NB];
    #pragma unroll
    for (int m=0;m<4;m++) af[m] = *(const s16x8*)&Als[(wr*64 + m*16 + li)*32 + lg*8];
    #pragma unroll
    for (int n=0;n<NB;n++) bf[n] = *(const s16x8*)&Bls[(wc*(BN/2) + n*16 + li)*32 + lg*8];
    #pragma unroll
    for (int m=0;m<4;m++)
      #pragma unroll
      for (int n=0;n<NB;n++)
        acc[m][n] = mfma16(af[m], bf[n], acc[m][n]);
  }
  #pragma unroll
  for (int n=0;n<NB;n++){
    int gcol = nbase + wc*(BN/2) + n*16 + li;
    float bv = bias[gcol];
    #pragma unroll
    for (int m=0;m<4;m++){
      #pragma unroll
      for (int r=0;r<4;r++){
        int grow = mbase + wr*64 + m*16 + 4*lg + r;
        float val = acc[m][n][r] + bv;
        if (ROPE){
          int t = grow & (S_LEN-1);
          int d = gcol & 63;
          const float* tp = tab + t*64 + (d & 62);
          float cv = tp[0], sv = tp[1];
          float other = __shfl_xor(val, 1);
          val = (d & 1) ? (other*sv + val*cv) : (val*cv - other*sv);
        }
        if (F32OUT) ((float*)Cv)[(size_t)grow*N + gcol] = val;
        else        ((ushort*)Cv)[(size_t)grow*N + gcol] = f2bf(val);
      }
    }
  }
}

// ---------------- Flash attention: single pass, stores seq + m/invl ----------------
__global__ __launch_bounds__(256) void flash_kernel(
    const ushort* __restrict__ qg, const ushort* __restrict__ kg,
    const ushort* __restrict__ vt, const int* __restrict__ lens,
    ushort* __restrict__ seq, float* __restrict__ mbuf, float* __restrict__ lbuf){
  __shared__ ushort kls[64*72];
  __shared__ ushort vls[64*72];
  __shared__ ushort pls[64*72];
  int tid = threadIdx.x;
  int w = tid>>6, l = tid&63, lg = l>>4, li = l&15;
  int qbase = blockIdx.x*64;
  int qh = blockIdx.y;
  int n  = blockIdx.z;
  int h = qh>>2;
  int len = lens[n];
  const float L2E = 1.4426950408889634f;

  int trow = qbase + 16*w + li;
  const ushort* qp = qg + ((size_t)n*S_LEN + trow)*1024 + qh*64 + 8*lg;
  s16x8 qf0 = *(const s16x8*)qp;
  s16x8 qf1 = *(const s16x8*)(qp + 32);

  int sT = tid>>2, sdg = (tid&3)*16;
  const ushort* kp = kg + ((size_t)n*S_LEN + sT)*256 + h*64 + sdg;
  const ushort* vp = vt + ((size_t)((n*4+h)*64 + sT))*S_LEN + sdg;  // sT as d-row

  float m_r[4], l_r[4];
  f32x4 oacc[4];
  #pragma unroll
  for (int r=0;r<4;r++){ m_r[r] = -1e30f; l_r[r] = 0.f; }
  #pragma unroll
  for (int c=0;c<4;c++) oacc[c] = (f32x4){0.f,0.f,0.f,0.f};
  int Tlim = min(qbase + 63, len - 1);
  int nComp = (Tlim >> 6) + 1;

  for (int it=0; it<nComp; ++it){
    int Tb = it*64;
    __syncthreads();
    { const ushort* kpp = kp + (size_t)Tb*256;
      *(s16x8*)&kls[sT*72 + sdg]     = *(const s16x8*)kpp;
      *(s16x8*)&kls[sT*72 + sdg + 8] = *(const s16x8*)(kpp + 8);
      const ushort* vpp = vp + Tb;
      *(s16x8*)&vls[sT*72 + sdg]     = *(const s16x8*)vpp;
      *(s16x8*)&vls[sT*72 + sdg + 8] = *(const s16x8*)(vpp + 8);
    }
    __syncthreads();
    f32x4 sc[4];
    #pragma unroll
    for (int c=0;c<4;c++) sc[c] = (f32x4){0.f,0.f,0.f,0.f};
    #pragma unroll
    for (int c=0;c<4;c++){
      s16x8 b0 = *(const s16x8*)&kls[(16*c+li)*72 + 8*lg];
      s16x8 b1 = *(const s16x8*)&kls[(16*c+li)*72 + 8*lg + 32];
      sc[c] = mfma16(qf0, b0, sc[c]);
      sc[c] = mfma16(qf1, b1, sc[c]);
    }
    #pragma unroll
    for (int c=0;c<4;c++){
      int Tg = Tb + 16*c + li;
      bool colp = Tg < len;
      #pragma unroll
      for (int r=0;r<4;r++){
        int tg = qbase + 16*w + 4*lg + r;
        sc[c][r] = (colp && Tg <= tg) ? sc[c][r]*0.125f : -1e30f;
      }
    }
    float sf[4];
    #pragma unroll
    for (int r=0;r<4;r++){
      float tmax = fmaxf(fmaxf(sc[0][r], sc[1][r]), fmaxf(sc[2][r], sc[3][r]));
      for (int msk=1; msk<16; msk<<=1) tmax = fmaxf(tmax, __shfl_xor(tmax, msk));
      float mn = fmaxf(m_r[r], tmax);
      #pragma unroll
      for (int c=0;c<4;c++) sc[c][r] = exp2f((sc[c][r]-mn)*L2E);
      float ssum = sc[0][r]+sc[1][r]+sc[2][r]+sc[3][r];
      for (int msk=1; msk<16; msk<<=1) ssum += __shfl_xor(ssum, msk);
      sf[r] = exp2f((m_r[r]-mn)*L2E);
      l_r[r] = l_r[r]*sf[r] + ssum;
      m_r[r] = mn;
    }
    #pragma unroll
    for (int c=0;c<4;c++)
      #pragma unroll
      for (int r=0;r<4;r++) oacc[c][r] *= sf[r];
    #pragma unroll
    for (int c=0;c<4;c++)
      #pragma unroll
      for (int r=0;r<4;r++)
        pls[(16*w + 4*lg + r)*72 + 16*c + li] = f2bf(sc[c][r]);
    #pragma unroll
    for (int f=0; f<2; f++){
      s16x8 pa = *(const s16x8*)&pls[(16*w + li)*72 + 8*lg + 32*f];
      #pragma unroll
      for (int c=0;c<4;c++){
        s16x8 vf = *(const s16x8*)&vls[(16*c+li)*72 + 8*lg + 32*f];
        oacc[c] = mfma16(pa, vf, oacc[c]);
      }
    }
  }

  float inv_l[4];
  #pragma unroll
  for (int r=0;r<4;r++) inv_l[r] = 1.0f / l_r[r];
  #pragma unroll
  for (int c=0;c<4;c++){
    #pragma unroll
    for (int r=0;r<4;r++){
      int tg = qbase + 16*w + 4*lg + r;
      seq[((size_t)n*S_LEN + tg)*1024 + qh*64 + 16*c + li] = f2bf(oacc[c][r]*inv_l[r]);
    }
  }
  int zi = n*16 + qh;
  if (li == 0){
    #pragma unroll
    for (int r=0;r<4;r++){
      int tg = qbase + 16*w + 4*lg + r;
      mbuf[(size_t)zi*S_LEN + tg] = m_r[r];
      lbuf[(size_t)zi*S_LEN + tg] = inv_l[r];
    }
  }
}

// ---------------- attn_viz writer: one 64q x 64T tile per block ----------------
__global__ __launch_bounds__(256) void viz_kernel(
    const ushort* __restrict__ qg, const ushort* __restrict__ kg,
    const int* __restrict__ lens, const float* __restrict__ mbuf,
    const float* __restrict__ lbuf, float* __restrict__ viz){
  __shared__ ushort kls[64*72];
  __shared__ float pfs[64*72];
  int tid = threadIdx.x;
  int Tb = blockIdx.x*64;
  int qbase = blockIdx.y*64;
  int zi = blockIdx.z;
  int n = zi>>4, qh = zi&15;
  int h = qh>>2, H = qh&3;
  int len = lens[n];
  float* vizp = viz + (size_t)((n*4 + H)*4 + h) * S_LEN * S_LEN;

  if (Tb > qbase + 63 || Tb >= len){
    int row = qbase + (tid>>2);
    float* zp = vizp + (size_t)row*S_LEN + Tb + (tid&3)*16;
    f32x4 zv = (f32x4){0.f,0.f,0.f,0.f};
    #pragma unroll
    for (int u=0;u<4;u++) *(f32x4*)(zp + 4*u) = zv;
    return;
  }

  int w = tid>>6, l = tid&63, lg = l>>4, li = l&15;
  const float L2E = 1.4426950408889634f;
  int trow = qbase + 16*w + li;
  const ushort* qp = qg + ((size_t)n*S_LEN + trow)*1024 + qh*64 + 8*lg;
  s16x8 qf0 = *(const s16x8*)qp;
  s16x8 qf1 = *(const s16x8*)(qp + 32);
  int sT = tid>>2, sdg = (tid&3)*16;
  const ushort* kpp = kg + ((size_t)n*S_LEN + Tb + sT)*256 + h*64 + sdg;
  *(s16x8*)&kls[sT*72 + sdg]     = *(const s16x8*)kpp;
  *(s16x8*)&kls[sT*72 + sdg + 8] = *(const s16x8*)(kpp + 8);

  float m_r[4], il_r[4];
  #pragma unroll
  for (int r=0;r<4;r++){
    int tg = qbase + 16*w + 4*lg + r;
    m_r[r]  = mbuf[(size_t)zi*S_LEN + tg];
    il_r[r] = lbuf[(size_t)zi*S_LEN + tg];
  }
  __syncthreads();

  f32x4 sc[4];
  #pragma unroll
  for (int c=0;c<4;c++) sc[c] = (f32x4){0.f,0.f,0.f,0.f};
  #pragma unroll
  for (int c=0;c<4;c++){
    s16x8 b0 = *(const s16x8*)&kls[(16*c+li)*72 + 8*lg];
    s16x8 b1 = *(const s16x8*)&kls[(16*c+li)*72 + 8*lg + 32];
    sc[c] = mfma16(qf0, b0, sc[c]);
    sc[c] = mfma16(qf1, b1, sc[c]);
  }
  #pragma unroll
  for (int c=0;c<4;c++){
    int Tg = Tb + 16*c + li;
    bool colp = Tg < len;
    #pragma unroll
    for (int r=0;r<4;r++){
      int tg = qbase + 16*w + 4*lg + r;
      bool ok = colp && (Tg <= tg);
      float p = exp2f((sc[c][r]*0.125f - m_r[r])*L2E) * il_r[r];
      pfs[(16*w + 4*lg + r)*72 + 16*c + li] = ok ? p : 0.f;
    }
  }
  __syncthreads();
  int row = tid>>2, c4 = (tid&3)*4;
  float* op = vizp + (size_t)(qbase+row)*S_LEN + Tb + c4;
  #pragma unroll
  for (int u=0;u<4;u++)
    *(f32x4*)(op + 16*u) = *(f32x4*)&pfs[row*72 + c4 + 16*u];
}

extern "C" void kernel_launch(void* const* d_in, const int* in_sizes, int n_in,
                              void* d_out, int out_size, void* d_ws, size_t ws_size,
                              hipStream_t stream){
  const float* xq = (const float*)d_in[0];
  const float* xk = (const float*)d_in[1];
  const float* xv = (const float*)d_in[2];
  const int*  lens= (const int*)d_in[3];
  const float* g  = (const float*)d_in[4];
  const float* be = (const float*)d_in[5];
  const float* Wq = (const float*)d_in[6];
  const float* bq = (const float*)d_in[7];
  const float* Wk = (const float*)d_in[8];
  const float* bk = (const float*)d_in[9];
  const float* Wv = (const float*)d_in[10];
  const float* bv = (const float*)d_in[11];
  const float* Wo = (const float*)d_in[12];
  const float* bo = (const float*)d_in[13];

  ushort* ws  = (ushort*)d_ws;
  ushort* xnq = ws;                        // 4096x1024
  ushort* xnk = ws + 4194304;
  ushort* xnv = ws + 8388608;
  ushort* qb  = ws + 12582912;             // 4096x1024
  ushort* kb  = ws + 16777216;             // 4096x256
  ushort* vb  = ws + 17825792;             // 4096x256
  ushort* vt  = ws + 18874368;             // 512x2048 (V^T per n,h)
  ushort* WqT = ws + 19922944;             // 1024x1024
  ushort* WkT = ws + 20971520;             // 256x1024
  ushort* WvT = ws + 21233664;             // 256x1024
  ushort* WoT = ws + 21495808;             // 1024x1024
  float*  tab = (float*)(ws + 22544384);   // 2048x64 f32
  float*  mbuf= (float*)(ws + 22806528);   // 32x2048 f32
  float*  lbuf= (float*)(ws + 22937600);   // 32x2048 f32
  ushort* seqb = xnq;                      // alias: xnq dead after Q-proj

  float* outp = (float*)d_out;
  float* vizp = outp + (size_t)4194304;

  trig_kernel<<<256,256,0,stream>>>(tab);
  ln_kernel<<<4096,256,0,stream>>>(xq, g, be, xnq);
  ln_kernel<<<4096,256,0,stream>>>(xk, g, be, xnk);
  ln_kernel<<<4096,256,0,stream>>>(xv, g, be, xnv);
  wtr_kernel<<<dim3(32,32),256,0,stream>>>(Wq, WqT, 1024);
  wtr_kernel<<<dim3( 8,32),256,0,stream>>>(Wk, WkT, 256);
  wtr_kernel<<<dim3( 8,32),256,0,stream>>>(Wv, WvT, 256);
  wtr_kernel<<<dim3(32,32),256,0,stream>>>(Wo, WoT, 1024);
  gemm_kernel<128,true ,false><<<dim3(8,32),256,0,stream>>>(xnq, WqT, bq, tab, qb, 1024, 1024);
  gemm_kernel< 64,true ,false><<<dim3(4,32),256,0,stream>>>(xnk, WkT, bk, tab, kb,  256, 1024);
  gemm_kernel< 64,false,false><<<dim3(4,32),256,0,stream>>>(xnv, WvT, bv, tab, vb,  256, 1024);
  utr_kernel<<<dim3(32,8),256,0,stream>>>(vb, vt);
  flash_kernel<<<dim3(32,16,2),256,0,stream>>>(qb, kb, vt, lens, seqb, mbuf, lbuf);
  viz_kernel<<<dim3(32,32,32),256,0,stream>>>(qb, kb, lens, mbuf, lbuf, vizp);
  gemm_kernel<128,false,true ><<<dim3(8,32),256,0,stream>>>(seqb, WoT, bo, tab, (void*)outp, 1024, 1024);
}

// Round 5
// 847.547 us; speedup vs baseline: 1.0221x; 1.0221x over previous
//
#include <hip/hip_runtime.h>
#include <hip/hip_bf16.h>

#define S_LEN 2048
#define DM 1024

typedef __attribute__((ext_vector_type(8))) short s16x8;
typedef __attribute__((ext_vector_type(4))) float f32x4;
typedef __attribute__((ext_vector_type(4))) ushort u16x4;

__device__ __forceinline__ ushort f2bf(float f){
  union { float f; unsigned u; } v; v.f = f;
  unsigned r = (v.u + 0x7FFFu + ((v.u >> 16) & 1u)) >> 16;
  return (ushort)r;
}

__device__ __forceinline__ f32x4 mfma16(s16x8 a, s16x8 b, f32x4 c){
  return __builtin_amdgcn_mfma_f32_16x16x32_bf16(a, b, c, 0, 0, 0);
}

__device__ __forceinline__ void gl_lds16(const ushort* g, ushort* l){
  __builtin_amdgcn_global_load_lds(
      (const __attribute__((address_space(1))) unsigned int*)g,
      (__attribute__((address_space(3))) unsigned int*)l, 16, 0, 0);
}

// ---------------- RoPE cos/sin table ----------------
__global__ __launch_bounds__(256) void trig_kernel(float* __restrict__ tab){
  int idx = blockIdx.x*256 + threadIdx.x;    // 2048*32 entries
  int t = idx >> 5, i2 = idx & 31;
  float inv = exp2f(-(float)i2 * 0.4152410118609203f);  // log2(10000)/32
  float ang = (float)t * inv;
  tab[2*idx]   = cosf(ang);
  tab[2*idx+1] = sinf(ang);
}

// ---------------- LayerNorm x3: fp32 row -> bf16 row ----------------
__global__ __launch_bounds__(256) void ln3_kernel(const float* __restrict__ x0,
    const float* __restrict__ x1, const float* __restrict__ x2,
    const float* __restrict__ g, const float* __restrict__ be, ushort* __restrict__ o){
  int row = blockIdx.x;
  int tid = threadIdx.x;
  const float* xs = (blockIdx.y==0) ? x0 : (blockIdx.y==1) ? x1 : x2;
  const float* xr = xs + (size_t)row*DM;
  float4 xv = *(const float4*)(xr + tid*4);
  float s  = xv.x+xv.y+xv.z+xv.w;
  float s2 = xv.x*xv.x+xv.y*xv.y+xv.z*xv.z+xv.w*xv.w;
  for (int m=1;m<64;m<<=1){ s += __shfl_xor(s,m); s2 += __shfl_xor(s2,m); }
  __shared__ float red[8];
  int w = tid>>6, l = tid&63;
  if (l==0){ red[w]=s; red[4+w]=s2; }
  __syncthreads();
  float ts = red[0]+red[1]+red[2]+red[3];
  float t2 = red[4]+red[5]+red[6]+red[7];
  float mu  = ts*(1.0f/DM);
  float var = t2*(1.0f/DM) - mu*mu;
  float rs  = rsqrtf(var + 1e-5f);
  float vals[4] = {xv.x,xv.y,xv.z,xv.w};
  const float* gp = g + tid*4;
  const float* bp = be + tid*4;
  u16x4 ov;
  #pragma unroll
  for (int j=0;j<4;j++) ov[j] = f2bf((vals[j]-mu)*rs*gp[j] + bp[j]);
  *(u16x4*)(o + (size_t)blockIdx.y*4194304 + (size_t)row*DM + tid*4) = ov;
}

// ---------------- Weight transpose + bf16: in[1024][N] -> out[N][1024] ----------------
__global__ __launch_bounds__(256) void wtr_kernel(const float* __restrict__ in,
    ushort* __restrict__ out, int N){
  __shared__ float lsf[32][36];
  int tid = threadIdx.x;
  int n0 = blockIdx.x*32, k0 = blockIdx.y*32;
  int kr = tid>>3, nc = (tid&7)*4;
  float4 v = *(const float4*)(in + (size_t)(k0+kr)*N + n0 + nc);
  *(float4*)&lsf[kr][nc] = v;
  __syncthreads();
  int nr = tid>>3, kc = (tid&7)*4;
  u16x4 o;
  #pragma unroll
  for (int j=0;j<4;j++) o[j] = f2bf(lsf[kc+j][nr]);
  *(u16x4*)(out + (size_t)(n0+nr)*DM + k0 + kc) = o;
}

// ---------------- V transpose: kvb[n][T][256+h*64+d] -> vt[(n*4+h)*64+d][T] ----------------
__global__ __launch_bounds__(256) void utr_kernel(const ushort* __restrict__ kvb,
    ushort* __restrict__ vt){
  __shared__ ushort lst[64*72];
  int tid = threadIdx.x;
  int t0 = blockIdx.x*64;
  int y = blockIdx.y; int n = y>>2, h = y&3;
  int Tr = tid>>2, dg = (tid&3)*16;
  const ushort* ip = kvb + ((size_t)(n*S_LEN + t0 + Tr))*512 + 256 + h*64 + dg;
  *(s16x8*)&lst[Tr*72 + dg]     = *(const s16x8*)ip;
  *(s16x8*)&lst[Tr*72 + dg + 8] = *(const s16x8*)(ip+8);
  __syncthreads();
  int d = tid>>2, Tg = (tid&3)*16;
  ushort* op = vt + ((size_t)(y*64 + d))*S_LEN + t0 + Tg;
  #pragma unroll
  for (int q=0;q<4;q++){
    u16x4 o;
    #pragma unroll
    for (int j=0;j<4;j++) o[j] = lst[(Tg+4*q+j)*72 + d];
    *(u16x4*)(op + 4*q) = o;
  }
}

// ---------------- GEMM: C[M x N] = A[M x K] * BT[N x K]^T + bias ----------------
// MODE 1: RoPE, bf16 out (Q).  MODE 2: fused KV (A-select by nbase, RoPE iff col<256).
// MODE 3: f32 out + bias (Wo).
template<int BM, int MODE>
__global__ __launch_bounds__(256) void gemm_kernel(
    const ushort* __restrict__ A, const ushort* __restrict__ A2,
    const ushort* __restrict__ BT, const float* __restrict__ bias,
    const float* __restrict__ bias2, const float* __restrict__ tab,
    void* __restrict__ Cv, int N, int K){
  constexpr int MF = 2;
  constexpr int NF = (BM == 128) ? 4 : 2;
  constexpr int ACALLS = BM/32;
  __shared__ ushort Als[BM*64];
  __shared__ ushort Bls[64*64];
  int tid = threadIdx.x;
  int w = tid>>6, l = tid&63, lg = l>>4, li = l&15;
  int wrow = (BM==128) ? w*32 : (w>>1)*32;
  int wcol = (BM==128) ? 0 : (w&1)*32;
  int mbase = blockIdx.y*BM, nbase = blockIdx.x*64;
  const ushort* Ause = A;
  if (MODE==2 && nbase >= 256) Ause = A2;
  f32x4 acc[MF][NF];
  #pragma unroll
  for (int m=0;m<MF;m++)
    #pragma unroll
    for (int n=0;n<NF;n++) acc[m][n] = (f32x4){0.f,0.f,0.f,0.f};
  for (int kk=0; kk<K; kk+=64){
    __syncthreads();
    #pragma unroll
    for (int s=0;s<ACALLS;s++){
      int idx = s*256 + tid;
      int row = idx>>3, ch = idx&7;
      gl_lds16(Ause + (size_t)(mbase+row)*K + kk + 8*(ch ^ (row&7)),
               &Als[(size_t)(s*256 + w*64)*8]);
    }
    #pragma unroll
    for (int s=0;s<2;s++){
      int idx = s*256 + tid;
      int row = idx>>3, ch = idx&7;
      gl_lds16(BT + (size_t)(nbase+row)*K + kk + 8*(ch ^ (row&7)),
               &Bls[(size_t)(s*256 + w*64)*8]);
    }
    __syncthreads();
    #pragma unroll
    for (int f=0;f<2;f++){
      s16x8 af[MF], bfv[NF];
      #pragma unroll
      for (int m=0;m<MF;m++)
        af[m] = *(const s16x8*)&Als[(wrow+m*16+li)*64 + 8*((lg+4*f) ^ (li&7))];
      #pragma unroll
      for (int n=0;n<NF;n++)
        bfv[n] = *(const s16x8*)&Bls[(wcol+n*16+li)*64 + 8*((lg+4*f) ^ (li&7))];
      #pragma unroll
      for (int m=0;m<MF;m++)
        #pragma unroll
        for (int n=0;n<NF;n++)
          acc[m][n] = mfma16(af[m], bfv[n], acc[m][n]);
    }
  }
  bool doRope = (MODE==1) || (MODE==2 && nbase < 256);
  #pragma unroll
  for (int n=0;n<NF;n++){
    int gcol = nbase + wcol + n*16 + li;
    float bv0 = (MODE==2 && nbase>=256) ? bias2[gcol-256] : bias[gcol];
    #pragma unroll
    for (int m=0;m<MF;m++){
      #pragma unroll
      for (int r=0;r<4;r++){
        int grow = mbase + wrow + m*16 + 4*lg + r;
        float val = acc[m][n][r] + bv0;
        if (doRope){
          int t = grow & (S_LEN-1);
          int d = gcol & 63;
          const float* tp = tab + t*64 + (d & 62);
          float cv = tp[0], sv = tp[1];
          float other = __shfl_xor(val, 1);
          val = (d & 1) ? (other*sv + val*cv) : (val*cv - other*sv);
        }
        if (MODE==3) ((float*)Cv)[(size_t)grow*N + gcol] = val;
        else         ((ushort*)Cv)[(size_t)grow*N + gcol] = f2bf(val);
      }
    }
  }
}

// ---------------- Flash attention: KVBLK=128, single pass, stores seq + m/invl ----------------
__global__ __launch_bounds__(256) void flash_kernel(
    const ushort* __restrict__ qg, const ushort* __restrict__ kvb,
    const ushort* __restrict__ vt, const int* __restrict__ lens,
    ushort* __restrict__ seq, float* __restrict__ mbuf, float* __restrict__ lbuf){
  __shared__ ushort kls[128*72];
  __shared__ ushort vls[64*136];
  __shared__ ushort pls[64*136];
  int tid = threadIdx.x;
  int w = tid>>6, l = tid&63, lg = l>>4, li = l&15;
  int qbase = blockIdx.x*64;
  int qh = blockIdx.y;
  int n  = blockIdx.z;
  int h = qh>>2;
  int len = lens[n];
  const float L2E = 1.4426950408889634f;

  int trow = qbase + 16*w + li;
  const ushort* qp = qg + ((size_t)n*S_LEN + trow)*1024 + qh*64 + 8*lg;
  s16x8 qf0 = *(const s16x8*)qp;
  s16x8 qf1 = *(const s16x8*)(qp + 32);

  // staging indices
  int sT2 = tid>>1, sd2 = (tid&1)*32;             // K: row, 32-short half
  int dv  = tid>>2, tc  = (tid&3)*32;             // V: d-row, 32-T chunk
  const ushort* kp = kvb + ((size_t)n*S_LEN + sT2)*512 + h*64 + sd2;
  const ushort* vp = vt + ((size_t)((n*4+h)*64 + dv))*S_LEN + tc;

  float m_r[4], l_r[4];
  f32x4 oacc[4];
  #pragma unroll
  for (int r=0;r<4;r++){ m_r[r] = -1e30f; l_r[r] = 0.f; }
  #pragma unroll
  for (int c=0;c<4;c++) oacc[c] = (f32x4){0.f,0.f,0.f,0.f};
  int Tlim = min(qbase + 63, len - 1);
  int nR = (Tlim >> 7) + 1;

  for (int it=0; it<nR; ++it){
    int Tb = it*128;
    __syncthreads();
    { const ushort* kpp = kp + (size_t)Tb*512;
      #pragma unroll
      for (int j=0;j<4;j++)
        *(s16x8*)&kls[sT2*72 + sd2 + 8*j] = *(const s16x8*)(kpp + 8*j);
      const ushort* vpp = vp + Tb;
      #pragma unroll
      for (int j=0;j<4;j++)
        *(s16x8*)&vls[dv*136 + tc + 8*j] = *(const s16x8*)(vpp + 8*j);
    }
    __syncthreads();
    f32x4 sc[8];
    #pragma unroll
    for (int c=0;c<8;c++) sc[c] = (f32x4){0.f,0.f,0.f,0.f};
    __builtin_amdgcn_s_setprio(1);
    #pragma unroll
    for (int c=0;c<8;c++){
      s16x8 b0 = *(const s16x8*)&kls[(16*c+li)*72 + 8*lg];
      s16x8 b1 = *(const s16x8*)&kls[(16*c+li)*72 + 8*lg + 32];
      sc[c] = mfma16(qf0, b0, sc[c]);
      sc[c] = mfma16(qf1, b1, sc[c]);
    }
    __builtin_amdgcn_s_setprio(0);
    #pragma unroll
    for (int c=0;c<8;c++){
      int Tg = Tb + 16*c + li;
      bool colp = Tg < len;
      #pragma unroll
      for (int r=0;r<4;r++){
        int tg = qbase + 16*w + 4*lg + r;
        sc[c][r] = (colp && Tg <= tg) ? sc[c][r]*0.125f : -1e30f;
      }
    }
    float sf[4];
    #pragma unroll
    for (int r=0;r<4;r++){
      float tmax = sc[0][r];
      #pragma unroll
      for (int c=1;c<8;c++) tmax = fmaxf(tmax, sc[c][r]);
      for (int msk=1; msk<16; msk<<=1) tmax = fmaxf(tmax, __shfl_xor(tmax, msk));
      float mn = fmaxf(m_r[r], tmax);
      float ssum = 0.f;
      #pragma unroll
      for (int c=0;c<8;c++){ sc[c][r] = exp2f((sc[c][r]-mn)*L2E); ssum += sc[c][r]; }
      for (int msk=1; msk<16; msk<<=1) ssum += __shfl_xor(ssum, msk);
      sf[r] = exp2f((m_r[r]-mn)*L2E);
      l_r[r] = l_r[r]*sf[r] + ssum;
      m_r[r] = mn;
    }
    #pragma unroll
    for (int c=0;c<4;c++)
      #pragma unroll
      for (int r=0;r<4;r++) oacc[c][r] *= sf[r];
    #pragma unroll
    for (int c=0;c<8;c++)
      #pragma unroll
      for (int r=0;r<4;r++)
        pls[(16*w + 4*lg + r)*136 + 16*c + li] = f2bf(sc[c][r]);
    __builtin_amdgcn_s_setprio(1);
    #pragma unroll
    for (int f=0; f<4; f++){
      s16x8 pa = *(const s16x8*)&pls[(16*w + li)*136 + 8*lg + 32*f];
      #pragma unroll
      for (int c=0;c<4;c++){
        s16x8 vf = *(const s16x8*)&vls[(16*c+li)*136 + 8*lg + 32*f];
        oacc[c] = mfma16(pa, vf, oacc[c]);
      }
    }
    __builtin_amdgcn_s_setprio(0);
  }

  float inv_l[4];
  #pragma unroll
  for (int r=0;r<4;r++) inv_l[r] = 1.0f / l_r[r];
  #pragma unroll
  for (int c=0;c<4;c++){
    #pragma unroll
    for (int r=0;r<4;r++){
      int tg = qbase + 16*w + 4*lg + r;
      seq[((size_t)n*S_LEN + tg)*1024 + qh*64 + 16*c + li] = f2bf(oacc[c][r]*inv_l[r]);
    }
  }
  int zi = n*16 + qh;
  if (li == 0){
    #pragma unroll
    for (int r=0;r<4;r++){
      int tg = qbase + 16*w + 4*lg + r;
      mbuf[(size_t)zi*S_LEN + tg] = m_r[r];
      lbuf[(size_t)zi*S_LEN + tg] = inv_l[r];
    }
  }
}

// ---------------- attn_viz writer: 64q x 256T per block, direct stores ----------------
__global__ __launch_bounds__(256) void viz_kernel(
    const ushort* __restrict__ qg, const ushort* __restrict__ kvb,
    const int* __restrict__ lens, const float* __restrict__ mbuf,
    const float* __restrict__ lbuf, float* __restrict__ viz){
  __shared__ ushort kls[64*72];
  int tid = threadIdx.x;
  int Tb0 = blockIdx.x*256;
  int qbase = blockIdx.y*64;
  int zi = blockIdx.z;
  int n = zi>>4, qh = zi&15;
  int h = qh>>2, H = qh&3;
  int len = lens[n];
  float* vizp = viz + (size_t)((n*4 + H)*4 + h) * S_LEN * S_LEN;
  int w = tid>>6, l = tid&63, lg = l>>4, li = l&15;
  const float L2E = 1.4426950408889634f;

  bool anyComp = (Tb0 <= qbase + 63) && (Tb0 < len);
  s16x8 qf0, qf1;
  float m_r[4], il_r[4];
  if (anyComp){
    int trow = qbase + 16*w + li;
    const ushort* qp = qg + ((size_t)n*S_LEN + trow)*1024 + qh*64 + 8*lg;
    qf0 = *(const s16x8*)qp;
    qf1 = *(const s16x8*)(qp + 32);
    #pragma unroll
    for (int r=0;r<4;r++){
      int tg = qbase + 16*w + 4*lg + r;
      m_r[r]  = mbuf[(size_t)zi*S_LEN + tg];
      il_r[r] = lbuf[(size_t)zi*S_LEN + tg];
    }
  }

  int sT = tid>>2, sdg = (tid&3)*16;
  for (int s=0; s<4; ++s){
    int Tb = Tb0 + s*64;
    bool zero = (Tb > qbase + 63) || (Tb >= len);
    if (zero){
      int row = qbase + (tid>>2);
      float* zp = vizp + (size_t)row*S_LEN + Tb + (tid&3)*16;
      f32x4 zv = (f32x4){0.f,0.f,0.f,0.f};
      #pragma unroll
      for (int u=0;u<4;u++) *(f32x4*)(zp + 4*u) = zv;
      continue;
    }
    __syncthreads();
    { const ushort* kpp = kvb + ((size_t)n*S_LEN + Tb + sT)*512 + h*64 + sdg;
      *(s16x8*)&kls[sT*72 + sdg]     = *(const s16x8*)kpp;
      *(s16x8*)&kls[sT*72 + sdg + 8] = *(const s16x8*)(kpp + 8);
    }
    __syncthreads();
    f32x4 sc[4];
    #pragma unroll
    for (int c=0;c<4;c++) sc[c] = (f32x4){0.f,0.f,0.f,0.f};
    #pragma unroll
    for (int c=0;c<4;c++){
      s16x8 b0 = *(const s16x8*)&kls[(16*c+li)*72 + 8*lg];
      s16x8 b1 = *(const s16x8*)&kls[(16*c+li)*72 + 8*lg + 32];
      sc[c] = mfma16(qf0, b0, sc[c]);
      sc[c] = mfma16(qf1, b1, sc[c]);
    }
    #pragma unroll
    for (int c=0;c<4;c++){
      int Tg = Tb + 16*c + li;
      bool colp = Tg < len;
      #pragma unroll
      for (int r=0;r<4;r++){
        int tg = qbase + 16*w + 4*lg + r;
        bool ok = colp && (Tg <= tg);
        float p = ok ? exp2f((sc[c][r]*0.125f - m_r[r])*L2E) * il_r[r] : 0.f;
        vizp[(size_t)tg*S_LEN + Tg] = p;
      }
    }
  }
}

extern "C" void kernel_launch(void* const* d_in, const int* in_sizes, int n_in,
                              void* d_out, int out_size, void* d_ws, size_t ws_size,
                              hipStream_t stream){
  const float* xq = (const float*)d_in[0];
  const float* xk = (const float*)d_in[1];
  const float* xv = (const float*)d_in[2];
  const int*  lens= (const int*)d_in[3];
  const float* g  = (const float*)d_in[4];
  const float* be = (const float*)d_in[5];
  const float* Wq = (const float*)d_in[6];
  const float* bq = (const float*)d_in[7];
  const float* Wk = (const float*)d_in[8];
  const float* bk = (const float*)d_in[9];
  const float* Wv = (const float*)d_in[10];
  const float* bv = (const float*)d_in[11];
  const float* Wo = (const float*)d_in[12];
  const float* bo = (const float*)d_in[13];

  ushort* ws  = (ushort*)d_ws;
  ushort* xnq = ws;                        // 4096x1024
  ushort* xnk = ws + 4194304;
  ushort* xnv = ws + 8388608;
  ushort* qb  = ws + 12582912;             // 4096x1024
  ushort* kvb = ws + 16777216;             // 4096x512 (K | V)
  ushort* vt  = ws + 18874368;             // 512x2048 (V^T per n,h)
  ushort* WqT = ws + 19922944;             // 1024x1024
  ushort* WkvT= ws + 20971520;             // 512x1024
  ushort* WoT = ws + 21495808;             // 1024x1024
  float*  tab = (float*)(ws + 22544384);   // 2048x64 f32
  float*  mbuf= (float*)(ws + 22806528);   // 32x2048 f32
  float*  lbuf= (float*)(ws + 22937600);   // 32x2048 f32
  ushort* seqb = xnq;                      // alias: xnq dead after Q-proj

  float* outp = (float*)d_out;
  float* vizp = outp + (size_t)4194304;

  trig_kernel<<<256,256,0,stream>>>(tab);
  ln3_kernel<<<dim3(4096,3),256,0,stream>>>(xq, xk, xv, g, be, xnq);
  wtr_kernel<<<dim3(32,32),256,0,stream>>>(Wq, WqT, 1024);
  wtr_kernel<<<dim3( 8,32),256,0,stream>>>(Wk, WkvT, 256);
  wtr_kernel<<<dim3( 8,32),256,0,stream>>>(Wv, WkvT + (size_t)256*1024, 256);
  wtr_kernel<<<dim3(32,32),256,0,stream>>>(Wo, WoT, 1024);
  gemm_kernel<128,1><<<dim3(16,32),256,0,stream>>>(xnq, nullptr, WqT, bq, nullptr, tab, qb, 1024, 1024);
  gemm_kernel< 64,2><<<dim3( 8,64),256,0,stream>>>(xnk, xnv, WkvT, bk, bv, tab, kvb, 512, 1024);
  utr_kernel<<<dim3(32,8),256,0,stream>>>(kvb, vt);
  flash_kernel<<<dim3(32,16,2),256,0,stream>>>(qb, kvb, vt, lens, seqb, mbuf, lbuf);
  viz_kernel<<<dim3(8,32,32),256,0,stream>>>(qb, kvb, lens, mbuf, lbuf, vizp);
  gemm_kernel<128,3><<<dim3(16,32),256,0,stream>>>(seqb, nullptr, WoT, bo, nullptr, tab, (void*)outp, 1024, 1024);
}